// Round 1
// baseline (442.781 us; speedup 1.0000x reference)
//
#include <hip/hip_runtime.h>
#include <hip/hip_bf16.h>

#define NB  4
#define NC  256
#define NC8 32
#define NHW 4096

typedef __attribute__((ext_vector_type(8))) short bf16x8;
typedef __attribute__((ext_vector_type(4))) float f32x4;

__device__ __forceinline__ unsigned short f2bf(float f) {
    union { float f; unsigned u; } v; v.f = f;
    unsigned r = v.u + 0x7fffu + ((v.u >> 16) & 1u);
    return (unsigned short)(r >> 16);
}

// q = q_w@x + q_b, k = k_w@g + k_b -> bf16, TRANSPOSED layout [b][n][32]
// block: 256 threads = 64 n_local x 4 o-groups (8 outputs each). grid: B*64
__global__ __launch_bounds__(256) void qk_proj(
    const float* __restrict__ x, const float* __restrict__ g,
    const float* __restrict__ qw, const float* __restrict__ qb,
    const float* __restrict__ kw, const float* __restrict__ kb,
    unsigned short* __restrict__ qt, unsigned short* __restrict__ kt)
{
    const int b  = blockIdx.x >> 6;
    const int nt = blockIdx.x & 63;
    const int nl = threadIdx.x & 63;
    const int og = threadIdx.x >> 6;          // o in [og*8, og*8+8)
    const int n  = nt * 64 + nl;
    const float* xp = x + (size_t)b * NC * NHW + n;
    const float* gp = g + (size_t)b * NC * NHW + n;

    float aq[8], ak[8];
#pragma unroll
    for (int j = 0; j < 8; ++j) { aq[j] = qb[og*8+j]; ak[j] = kb[og*8+j]; }

    for (int c = 0; c < NC; c += 4) {
        float xv0 = xp[(size_t)(c+0)*NHW], xv1 = xp[(size_t)(c+1)*NHW];
        float xv2 = xp[(size_t)(c+2)*NHW], xv3 = xp[(size_t)(c+3)*NHW];
        float gv0 = gp[(size_t)(c+0)*NHW], gv1 = gp[(size_t)(c+1)*NHW];
        float gv2 = gp[(size_t)(c+2)*NHW], gv3 = gp[(size_t)(c+3)*NHW];
#pragma unroll
        for (int j = 0; j < 8; ++j) {
            f32x4 wq = *(const f32x4*)(qw + (size_t)(og*8+j)*NC + c);
            f32x4 wk = *(const f32x4*)(kw + (size_t)(og*8+j)*NC + c);
            aq[j] = fmaf(wq[0], xv0, aq[j]); aq[j] = fmaf(wq[1], xv1, aq[j]);
            aq[j] = fmaf(wq[2], xv2, aq[j]); aq[j] = fmaf(wq[3], xv3, aq[j]);
            ak[j] = fmaf(wk[0], gv0, ak[j]); ak[j] = fmaf(wk[1], gv1, ak[j]);
            ak[j] = fmaf(wk[2], gv2, ak[j]); ak[j] = fmaf(wk[3], gv3, ak[j]);
        }
    }
    bf16x8 oq, ok;
#pragma unroll
    for (int j = 0; j < 8; ++j) { oq[j] = (short)f2bf(aq[j]); ok[j] = (short)f2bf(ak[j]); }
    *(bf16x8*)(qt + ((size_t)b*NHW + n)*NC8 + og*8) = oq;
    *(bf16x8*)(kt + ((size_t)b*NHW + n)*NC8 + og*8) = ok;
}

// v = v_w@g + v_b -> bf16 [b][c][hw]
// block: 256 = 64 n_local x 4 og (16 c-outputs each); grid: (B*64, C/64)
__global__ __launch_bounds__(256) void v_proj(
    const float* __restrict__ g, const float* __restrict__ vw,
    const float* __restrict__ vb, unsigned short* __restrict__ vbf)
{
    const int b  = blockIdx.x >> 6;
    const int nt = blockIdx.x & 63;
    const int cc = blockIdx.y;
    const int nl = threadIdx.x & 63;
    const int og = threadIdx.x >> 6;
    const int n   = nt*64 + nl;
    const int co0 = cc*64 + og*16;
    const float* gp = g + (size_t)b*NC*NHW + n;

    float a[16];
#pragma unroll
    for (int i = 0; i < 16; ++i) a[i] = vb[co0+i];
    for (int c = 0; c < NC; c += 4) {
        float gv0 = gp[(size_t)(c+0)*NHW], gv1 = gp[(size_t)(c+1)*NHW];
        float gv2 = gp[(size_t)(c+2)*NHW], gv3 = gp[(size_t)(c+3)*NHW];
#pragma unroll
        for (int i = 0; i < 16; ++i) {
            f32x4 w = *(const f32x4*)(vw + (size_t)(co0+i)*NC + c);
            a[i] = fmaf(w[0], gv0, a[i]); a[i] = fmaf(w[1], gv1, a[i]);
            a[i] = fmaf(w[2], gv2, a[i]); a[i] = fmaf(w[3], gv3, a[i]);
        }
    }
#pragma unroll
    for (int i = 0; i < 16; ++i)
        vbf[((size_t)b*NC + co0 + i)*NHW + n] = f2bf(a[i]);
}

// Flash attention: block = (b, 64-row n-tile), 4 waves x 16 q-rows.
// energy = Q.K^T via mfma 16x16x32 (d=32 exactly); online softmax w/ defer-max;
// P routed through per-wave LDS tile (stride 40 -> 16B-aligned, low-conflict);
// PV mfma over 16 c-tiles; epilogue fuses gamma*out/l + x with float4 stores.
__global__ __launch_bounds__(256) void attn(
    const unsigned short* __restrict__ qt, const unsigned short* __restrict__ kt,
    const unsigned short* __restrict__ vbf, const float* __restrict__ x,
    const float* __restrict__ gamma, float* __restrict__ out)
{
    const int b    = blockIdx.x >> 6;
    const int nt   = blockIdx.x & 63;
    const int tid  = threadIdx.x;
    const int w    = tid >> 6;
    const int lane = tid & 63;
    const int l16  = lane & 15;
    const int g4   = lane >> 4;
    const int n0   = nt*64 + w*16;

    __shared__ unsigned short plds[4][16][40];  // stride 40 bf16 = 80B (16B aligned rows)

    const bf16x8 qfrag = *(const bf16x8*)(qt + ((size_t)b*NHW + n0 + l16)*NC8 + g4*8);
    const unsigned short* kbase = kt  + (size_t)b*NHW*NC8;
    const unsigned short* vrow  = vbf + (size_t)b*NC*NHW + (size_t)l16*NHW + g4*8;

    f32x4 z = {0.f, 0.f, 0.f, 0.f};
    f32x4 acc[16];
#pragma unroll
    for (int i = 0; i < 16; ++i) acc[i] = z;
    float mrun[4] = {-1e30f, -1e30f, -1e30f, -1e30f};
    float lrun[4] = {0.f, 0.f, 0.f, 0.f};

    for (int m0 = 0; m0 < NHW; m0 += 32) {
        bf16x8 kf0 = *(const bf16x8*)(kbase + (size_t)(m0      + l16)*NC8 + g4*8);
        bf16x8 kf1 = *(const bf16x8*)(kbase + (size_t)(m0 + 16 + l16)*NC8 + g4*8);
        f32x4 e0 = __builtin_amdgcn_mfma_f32_16x16x32_bf16(qfrag, kf0, z, 0, 0, 0);
        f32x4 e1 = __builtin_amdgcn_mfma_f32_16x16x32_bf16(qfrag, kf1, z, 0, 0, 0);

        // row-max across the 16 lanes of each group (rows n = n0 + g4*4 + r)
        float pm[4];
#pragma unroll
        for (int r = 0; r < 4; ++r) pm[r] = fmaxf(e0[r], e1[r]);
#pragma unroll
        for (int s = 1; s < 16; s <<= 1) {
#pragma unroll
            for (int r = 0; r < 4; ++r) pm[r] = fmaxf(pm[r], __shfl_xor(pm[r], s));
        }

        // defer-max (T13): only rescale when some row's max grew by > 8
        bool need = false;
#pragma unroll
        for (int r = 0; r < 4; ++r) need = need || (pm[r] - mrun[r] > 8.0f);
        if (__any((int)need)) {
#pragma unroll
            for (int r = 0; r < 4; ++r) {
                float mn = fmaxf(mrun[r], pm[r]);
                float sc = __expf(mrun[r] - mn);
                mrun[r] = mn;
                lrun[r] *= sc;
#pragma unroll
                for (int ct = 0; ct < 16; ++ct) acc[ct][r] *= sc;
            }
        }

        float p0[4], p1[4], ps[4];
#pragma unroll
        for (int r = 0; r < 4; ++r) {
            p0[r] = __expf(e0[r] - mrun[r]);
            p1[r] = __expf(e1[r] - mrun[r]);
            ps[r] = p0[r] + p1[r];
        }
#pragma unroll
        for (int s = 1; s < 16; s <<= 1) {
#pragma unroll
            for (int r = 0; r < 4; ++r) ps[r] += __shfl_xor(ps[r], s);
        }
#pragma unroll
        for (int r = 0; r < 4; ++r) lrun[r] += ps[r];

        // P (D-layout: row=g4*4+r, col=l16) -> LDS -> A-frag layout (row=l16, 8 contiguous m)
#pragma unroll
        for (int r = 0; r < 4; ++r) {
            plds[w][g4*4+r][l16]    = f2bf(p0[r]);
            plds[w][g4*4+r][16+l16] = f2bf(p1[r]);
        }
        bf16x8 pa = *(const bf16x8*)&plds[w][l16][g4*8];

        const unsigned short* vp = vrow + m0;
#pragma unroll
        for (int ct = 0; ct < 16; ++ct) {
            bf16x8 vf = *(const bf16x8*)(vp + (size_t)ct*16*NHW);
            acc[ct] = __builtin_amdgcn_mfma_f32_16x16x32_bf16(pa, vf, acc[ct], 0, 0, 0);
        }
    }

    const float ga = gamma[0];
    float il[4];
#pragma unroll
    for (int r = 0; r < 4; ++r) il[r] = ga / lrun[r];
#pragma unroll
    for (int ct = 0; ct < 16; ++ct) {
        const int c = ct*16 + l16;
        const size_t o = ((size_t)b*NC + c)*NHW + (size_t)n0 + g4*4;
        f32x4 xv = *(const f32x4*)(x + o);
        f32x4 res;
#pragma unroll
        for (int r = 0; r < 4; ++r) res[r] = fmaf(acc[ct][r], il[r], xv[r]);
        *(f32x4*)(out + o) = res;
    }
}

extern "C" void kernel_launch(void* const* d_in, const int* in_sizes, int n_in,
                              void* d_out, int out_size, void* d_ws, size_t ws_size,
                              hipStream_t stream) {
    const float* x     = (const float*)d_in[0];
    const float* g     = (const float*)d_in[1];
    const float* qw    = (const float*)d_in[2];
    const float* qb    = (const float*)d_in[3];
    const float* kw    = (const float*)d_in[4];
    const float* kb    = (const float*)d_in[5];
    const float* vw    = (const float*)d_in[6];
    const float* vb    = (const float*)d_in[7];
    const float* gamma = (const float*)d_in[8];
    float* out = (float*)d_out;

    // workspace: qt (1MB) | kt (1MB) | vbf (8MB), all bf16 bit-patterns
    unsigned short* qt  = (unsigned short*)d_ws;
    unsigned short* kt  = qt + (size_t)NB*NHW*NC8;
    unsigned short* vbf = kt + (size_t)NB*NHW*NC8;

    qk_proj<<<NB*(NHW/64), 256, 0, stream>>>(x, g, qw, qb, kw, kb, qt, kt);
    v_proj <<<dim3(NB*(NHW/64), NC/64), 256, 0, stream>>>(g, vw, vb, vbf);
    attn   <<<NB*(NHW/64), 256, 0, stream>>>(qt, kt, vbf, x, gamma, out);
}

// Round 2
// 413.429 us; speedup vs baseline: 1.0710x; 1.0710x over previous
//
#include <hip/hip_runtime.h>
#include <hip/hip_bf16.h>

#define NB  4
#define NC  256
#define NC8 32
#define NHW 4096

typedef __attribute__((ext_vector_type(8))) short bf16x8;
typedef __attribute__((ext_vector_type(4))) float f32x4;

__device__ __forceinline__ unsigned short f2bf(float f) {
    union { float f; unsigned u; } v; v.f = f;
    unsigned r = v.u + 0x7fffu + ((v.u >> 16) & 1u);
    return (unsigned short)(r >> 16);
}

// Unified projection kernel. blockIdx.y: 0 -> q (from x), 1 -> k (from g),
// 2..9 -> v chunk (y-2)*32 (from g). 256 thr = 64 pixels x 4 og (8 outs each).
// grid (B*64, 10) = 2560 blocks -> ~10 waves/SIMD (latency hiding).
__global__ __launch_bounds__(256) void proj(
    const float* __restrict__ x, const float* __restrict__ g,
    const float* __restrict__ qw, const float* __restrict__ qb,
    const float* __restrict__ kw, const float* __restrict__ kb,
    const float* __restrict__ vw, const float* __restrict__ vb,
    unsigned short* __restrict__ qt, unsigned short* __restrict__ kt,
    unsigned short* __restrict__ vbf)
{
    const int b  = blockIdx.x >> 6;
    const int nt = blockIdx.x & 63;
    const int y  = blockIdx.y;
    const int nl = threadIdx.x & 63;
    const int og = threadIdx.x >> 6;
    const int n  = nt * 64 + nl;

    const float *in, *W, *bias;
    int row0;
    if (y == 0)      { in = x; W = qw; bias = qb; row0 = og * 8; }
    else if (y == 1) { in = g; W = kw; bias = kb; row0 = og * 8; }
    else             { in = g; W = vw; bias = vb; row0 = (y - 2) * 32 + og * 8; }

    const float* ip = in + (size_t)b * NC * NHW + n;

    float a[8];
#pragma unroll
    for (int j = 0; j < 8; ++j) a[j] = bias[row0 + j];

    for (int c = 0; c < NC; c += 4) {
        float v0 = ip[(size_t)(c+0)*NHW], v1 = ip[(size_t)(c+1)*NHW];
        float v2 = ip[(size_t)(c+2)*NHW], v3 = ip[(size_t)(c+3)*NHW];
#pragma unroll
        for (int j = 0; j < 8; ++j) {
            f32x4 w = *(const f32x4*)(W + (size_t)(row0 + j) * NC + c);
            a[j] = fmaf(w[0], v0, a[j]); a[j] = fmaf(w[1], v1, a[j]);
            a[j] = fmaf(w[2], v2, a[j]); a[j] = fmaf(w[3], v3, a[j]);
        }
    }

    if (y < 2) {
        bf16x8 o;
#pragma unroll
        for (int j = 0; j < 8; ++j) o[j] = (short)f2bf(a[j]);
        unsigned short* dst = (y == 0 ? qt : kt);
        *(bf16x8*)(dst + ((size_t)b * NHW + n) * NC8 + row0) = o;
    } else {
#pragma unroll
        for (int j = 0; j < 8; ++j)
            vbf[((size_t)b * NC + row0 + j) * NHW + n] = f2bf(a[j]);
    }
}

// Flash attention, in-block split-KV.
// Block = 1024 thr = 16 waves = 4 row-groups (16 q-rows) x 4 KV-splits (1024
// keys) -> 4 waves/SIMD (vs 1 before: the latency fix). Cross-split combine
// of (m,l,acc) through LDS; epilogue fuses gamma*out/L + x, float4 stores.
__global__ __launch_bounds__(1024, 4) void attn(
    const unsigned short* __restrict__ qt, const unsigned short* __restrict__ kt,
    const unsigned short* __restrict__ vbf, const float* __restrict__ x,
    const float* __restrict__ gamma, float* __restrict__ out)
{
    const int b    = blockIdx.x >> 6;
    const int nt   = blockIdx.x & 63;
    const int tid  = threadIdx.x;
    const int wv   = tid >> 6;        // 0..15
    const int rg   = wv & 3;          // row-group
    const int s    = wv >> 2;         // KV split
    const int lane = tid & 63;
    const int l16  = lane & 15;
    const int g4   = lane >> 4;
    const int n0   = nt * 64 + rg * 16;

    // LDS: plds (loop phase, 20.5KB) aliases clds (combine phase, 64KB)
    __shared__ alignas(16) char smraw[4 * 4 * 4 * 16 * 16 * 4];
    typedef unsigned short plds_row[16][40];
    plds_row* plds = (plds_row*)smraw;                    // [16 waves][16][40]
    float (*clds)[4][4][16][16] = (float (*)[4][4][16][16])smraw; // [rg][s][j][row][col]
    __shared__ float mlds[4][4][16];
    __shared__ float llds[4][4][16];

    const bf16x8 qfrag = *(const bf16x8*)(qt + ((size_t)b * NHW + n0 + l16) * NC8 + g4 * 8);
    const unsigned short* kbase = kt  + (size_t)b * NHW * NC8;
    const unsigned short* vrow  = vbf + (size_t)b * NC * NHW + (size_t)l16 * NHW + g4 * 8;

    f32x4 z = {0.f, 0.f, 0.f, 0.f};
    f32x4 acc[16];
#pragma unroll
    for (int i = 0; i < 16; ++i) acc[i] = z;
    float mrun[4] = {-1e30f, -1e30f, -1e30f, -1e30f};
    float lrun[4] = {0.f, 0.f, 0.f, 0.f};

    for (int m0 = s * 1024; m0 < (s + 1) * 1024; m0 += 32) {
        bf16x8 kf0 = *(const bf16x8*)(kbase + (size_t)(m0      + l16) * NC8 + g4 * 8);
        bf16x8 kf1 = *(const bf16x8*)(kbase + (size_t)(m0 + 16 + l16) * NC8 + g4 * 8);
        f32x4 e0 = __builtin_amdgcn_mfma_f32_16x16x32_bf16(qfrag, kf0, z, 0, 0, 0);
        f32x4 e1 = __builtin_amdgcn_mfma_f32_16x16x32_bf16(qfrag, kf1, z, 0, 0, 0);

        float pm[4];
#pragma unroll
        for (int r = 0; r < 4; ++r) pm[r] = fmaxf(e0[r], e1[r]);
#pragma unroll
        for (int st = 1; st < 16; st <<= 1) {
#pragma unroll
            for (int r = 0; r < 4; ++r) pm[r] = fmaxf(pm[r], __shfl_xor(pm[r], st));
        }

        bool need = false;
#pragma unroll
        for (int r = 0; r < 4; ++r) need = need || (pm[r] - mrun[r] > 8.0f);
        if (__any((int)need)) {
#pragma unroll
            for (int r = 0; r < 4; ++r) {
                float mn = fmaxf(mrun[r], pm[r]);
                float scl = __expf(mrun[r] - mn);
                mrun[r] = mn;
                lrun[r] *= scl;
#pragma unroll
                for (int ct = 0; ct < 16; ++ct) acc[ct][r] *= scl;
            }
        }

        float p0[4], p1[4], ps[4];
#pragma unroll
        for (int r = 0; r < 4; ++r) {
            p0[r] = __expf(e0[r] - mrun[r]);
            p1[r] = __expf(e1[r] - mrun[r]);
            ps[r] = p0[r] + p1[r];
        }
#pragma unroll
        for (int st = 1; st < 16; st <<= 1) {
#pragma unroll
            for (int r = 0; r < 4; ++r) ps[r] += __shfl_xor(ps[r], st);
        }
#pragma unroll
        for (int r = 0; r < 4; ++r) lrun[r] += ps[r];

        // P (D layout: row=g4*4+r, col=l16) -> LDS -> A-frag (row=l16, 8 contig m)
#pragma unroll
        for (int r = 0; r < 4; ++r) {
            plds[wv][g4*4+r][l16]      = f2bf(p0[r]);
            plds[wv][g4*4+r][16 + l16] = f2bf(p1[r]);
        }
        bf16x8 pa = *(const bf16x8*)&plds[wv][l16][g4 * 8];

        const unsigned short* vp = vrow + m0;
#pragma unroll
        for (int ct = 0; ct < 16; ++ct) {
            bf16x8 vf = *(const bf16x8*)(vp + (size_t)ct * 16 * NHW);
            acc[ct] = __builtin_amdgcn_mfma_f32_16x16x32_bf16(pa, vf, acc[ct], 0, 0, 0);
        }
    }

    // ---- cross-split combine ----
    if (l16 == 0) {
#pragma unroll
        for (int r = 0; r < 4; ++r) {
            mlds[rg][s][g4*4+r] = mrun[r];
            llds[rg][s][g4*4+r] = lrun[r];
        }
    }
    __syncthreads();

    const float ga = gamma[0];
    float sc[4], il[4];
#pragma unroll
    for (int r = 0; r < 4; ++r) {
        const int row = g4*4 + r;
        float m0_ = mlds[rg][0][row], m1_ = mlds[rg][1][row];
        float m2_ = mlds[rg][2][row], m3_ = mlds[rg][3][row];
        float M = fmaxf(fmaxf(m0_, m1_), fmaxf(m2_, m3_));
        float L = llds[rg][0][row] * __expf(m0_ - M)
                + llds[rg][1][row] * __expf(m1_ - M)
                + llds[rg][2][row] * __expf(m2_ - M)
                + llds[rg][3][row] * __expf(m3_ - M);
        sc[r] = __expf(mrun[r] - M);
        il[r] = ga / L;
    }

    for (int c0 = 0; c0 < 16; c0 += 4) {
        __syncthreads();   // previous chunk fully read / loop-phase plds dead
#pragma unroll
        for (int j = 0; j < 4; ++j) {
#pragma unroll
            for (int r = 0; r < 4; ++r)
                clds[rg][s][j][g4*4+r][l16] = acc[c0 + j][r] * sc[r];
        }
        __syncthreads();
        const int ct = c0 + s;      // this wave reduces c-tile j = s
        float sum[4];
#pragma unroll
        for (int r = 0; r < 4; ++r) {
            const int row = g4*4 + r;
            sum[r] = clds[rg][0][s][row][l16] + clds[rg][1][s][row][l16]
                   + clds[rg][2][s][row][l16] + clds[rg][3][s][row][l16];
        }
        const int c = ct * 16 + l16;
        const size_t o = ((size_t)b * NC + c) * NHW + (size_t)n0 + g4 * 4;
        f32x4 xv = *(const f32x4*)(x + o);
        f32x4 res;
#pragma unroll
        for (int r = 0; r < 4; ++r) res[r] = fmaf(sum[r], il[r], xv[r]);
        *(f32x4*)(out + o) = res;
    }
}

extern "C" void kernel_launch(void* const* d_in, const int* in_sizes, int n_in,
                              void* d_out, int out_size, void* d_ws, size_t ws_size,
                              hipStream_t stream) {
    const float* x     = (const float*)d_in[0];
    const float* g     = (const float*)d_in[1];
    const float* qw    = (const float*)d_in[2];
    const float* qb    = (const float*)d_in[3];
    const float* kw    = (const float*)d_in[4];
    const float* kb    = (const float*)d_in[5];
    const float* vw    = (const float*)d_in[6];
    const float* vb    = (const float*)d_in[7];
    const float* gamma = (const float*)d_in[8];
    float* out = (float*)d_out;

    unsigned short* qt  = (unsigned short*)d_ws;
    unsigned short* kt  = qt + (size_t)NB * NHW * NC8;
    unsigned short* vbf = kt + (size_t)NB * NHW * NC8;

    proj<<<dim3(NB * (NHW / 64), 10), 256, 0, stream>>>(x, g, qw, qb, kw, kb, vw, vb, qt, kt, vbf);
    attn<<<NB * (NHW / 64), 1024, 0, stream>>>(qt, kt, vbf, x, gamma, out);
}

// Round 4
// 169.817 us; speedup vs baseline: 2.6074x; 2.4346x over previous
//
#include <hip/hip_runtime.h>
#include <hip/hip_bf16.h>

#define NB  4
#define NC  256
#define NC8 32
#define NHW 4096
#define MSTEP 64

typedef __attribute__((ext_vector_type(8))) short bf16x8;
typedef __attribute__((ext_vector_type(4))) float f32x4;
typedef __attribute__((ext_vector_type(2))) unsigned u32x2;

__device__ __forceinline__ unsigned short f2bf(float f) {
    union { float f; unsigned u; } v; v.f = f;
    unsigned r = v.u + 0x7fffu + ((v.u >> 16) & 1u);
    return (unsigned short)(r >> 16);
}

// pack two floats -> bf16 pair (lo in low half), RNE
__device__ __forceinline__ unsigned packbf2(float lo, float hi) {
    __hip_bfloat162 h = __float22bfloat162_rn(make_float2(lo, hi));
    union { __hip_bfloat162 h; unsigned u; } cv; cv.h = h; return cv.u;
}

__device__ __forceinline__ void glds16(void* lds, const void* g) {
    __builtin_amdgcn_global_load_lds((const __attribute__((address_space(1))) unsigned int*)g,
                                     (__attribute__((address_space(3))) unsigned int*)lds, 16, 0, 0);
}
__device__ __forceinline__ void glds4(void* lds, const void* g) {
    __builtin_amdgcn_global_load_lds((const __attribute__((address_space(1))) unsigned int*)g,
                                     (__attribute__((address_space(3))) unsigned int*)lds, 4, 0, 0);
}

// ---------------- qk_proj: fp32 VALU (accuracy-critical path) ----------------
// q/k errors are amplified through softmax logits; keep them fp32 until the
// final bf16 store. Only 0.54 GF total. blockIdx.y: 0->q(x), 1->k(g).
// 512 thr = 64 px x 8 og (4 outs each); grid (256,2)=512 blocks -> 4 waves/SIMD.
__global__ __launch_bounds__(512) void qk_proj(
    const float* __restrict__ x, const float* __restrict__ g,
    const float* __restrict__ qw, const float* __restrict__ qb,
    const float* __restrict__ kw, const float* __restrict__ kb,
    unsigned short* __restrict__ qt, unsigned short* __restrict__ kt)
{
    const int b  = blockIdx.x >> 6;
    const int nt = blockIdx.x & 63;
    const int y  = blockIdx.y;
    const int px = threadIdx.x & 63;
    const int og = threadIdx.x >> 6;      // outs og*4 .. og*4+3
    const int n  = nt * 64 + px;

    const float* in   = y ? g  : x;
    const float* W    = y ? kw : qw;
    const float* bias = y ? kb : qb;
    unsigned short* dst = y ? kt : qt;

    const float* ip = in + (size_t)b * NC * NHW + n;

    float a[4];
#pragma unroll
    for (int j = 0; j < 4; ++j) a[j] = bias[og * 4 + j];

    for (int c = 0; c < NC; c += 4) {
        float v0 = ip[(size_t)(c+0)*NHW], v1 = ip[(size_t)(c+1)*NHW];
        float v2 = ip[(size_t)(c+2)*NHW], v3 = ip[(size_t)(c+3)*NHW];
#pragma unroll
        for (int j = 0; j < 4; ++j) {
            f32x4 w = *(const f32x4*)(W + (size_t)(og * 4 + j) * NC + c);
            a[j] = fmaf(w[0], v0, a[j]); a[j] = fmaf(w[1], v1, a[j]);
            a[j] = fmaf(w[2], v2, a[j]); a[j] = fmaf(w[3], v3, a[j]);
        }
    }
    u32x2 pk;
    pk[0] = packbf2(a[0], a[1]);
    pk[1] = packbf2(a[2], a[3]);
    *(u32x2*)(dst + ((size_t)b * NHW + n) * NC8 + og * 4) = pk;
}

// ---------------- v_proj: bf16 MFMA GEMM (error enters output linearly) -----
// blockIdx.y 0..7 -> v rows y*32. Block: 256 thr (4 waves),
// out-tile = 32 rows x 128 pixels, K=256 in 8 steps.
__global__ __launch_bounds__(256) void v_proj(
    const float* __restrict__ g, const float* __restrict__ vw,
    const float* __restrict__ vb, unsigned short* __restrict__ vbf)
{
    const int b   = blockIdx.x >> 5;      // NHW/128 = 32 tiles per batch
    const int pt  = blockIdx.x & 31;
    const int row0 = blockIdx.y * 32;
    const int tid = threadIdx.x;
    const int wv  = tid >> 6;
    const int lane = tid & 63;
    const int l16 = lane & 15;
    const int g4  = lane >> 4;
    const int px0 = pt * 128;

    __shared__ alignas(16) unsigned short WsL[32][264];   // 528B row (16B-mult)
    __shared__ alignas(16) unsigned short InL[128][32];   // [px][c] -> B-frag

    {
        const int wrow = tid >> 3;
        const int wcb  = (tid & 7) * 32;
        const float* wsrc = vw + (size_t)(row0 + wrow) * NC + wcb;
#pragma unroll
        for (int q = 0; q < 4; ++q) {
            f32x4 a  = *(const f32x4*)(wsrc + q * 8);
            f32x4 b2 = *(const f32x4*)(wsrc + q * 8 + 4);
            union { unsigned u[4]; bf16x8 v; } pk8;
            pk8.u[0] = packbf2(a[0],  a[1]);  pk8.u[1] = packbf2(a[2],  a[3]);
            pk8.u[2] = packbf2(b2[0], b2[1]); pk8.u[3] = packbf2(b2[2], b2[3]);
            *(bf16x8*)&WsL[wrow][wcb + q * 8] = pk8.v;
        }
    }
    __syncthreads();

    f32x4 z = {0.f, 0.f, 0.f, 0.f};
    f32x4 acc[2][2] = {{z, z}, {z, z}};   // [rt][ntl]

    const int spx = tid & 127;
    const int sch = (tid >> 7) * 16;

    for (int c0 = 0; c0 < NC; c0 += 32) {
        __syncthreads();
#pragma unroll
        for (int j = 0; j < 2; ++j) {
            float pv[8];
#pragma unroll
            for (int q = 0; q < 8; ++q)
                pv[q] = g[(size_t)b * NC * NHW + (size_t)(c0 + sch + j * 8 + q) * NHW + px0 + spx];
            union { unsigned u[4]; bf16x8 v; } pk8;
            pk8.u[0] = packbf2(pv[0], pv[1]); pk8.u[1] = packbf2(pv[2], pv[3]);
            pk8.u[2] = packbf2(pv[4], pv[5]); pk8.u[3] = packbf2(pv[6], pv[7]);
            *(bf16x8*)&InL[spx][sch + j * 8] = pk8.v;
        }
        __syncthreads();

        bf16x8 af0 = *(const bf16x8*)&WsL[l16][c0 + g4 * 8];
        bf16x8 af1 = *(const bf16x8*)&WsL[16 + l16][c0 + g4 * 8];
#pragma unroll
        for (int ntl = 0; ntl < 2; ++ntl) {
            const int nt = wv * 2 + ntl;
            bf16x8 bfg = *(const bf16x8*)&InL[nt * 16 + l16][g4 * 8];
            acc[0][ntl] = __builtin_amdgcn_mfma_f32_16x16x32_bf16(af0, bfg, acc[0][ntl], 0, 0, 0);
            acc[1][ntl] = __builtin_amdgcn_mfma_f32_16x16x32_bf16(af1, bfg, acc[1][ntl], 0, 0, 0);
        }
    }

#pragma unroll
    for (int rt = 0; rt < 2; ++rt) {
        f32x4 b4 = *(const f32x4*)(vb + row0 + rt * 16 + g4 * 4);
#pragma unroll
        for (int ntl = 0; ntl < 2; ++ntl) {
            const int n = px0 + (wv * 2 + ntl) * 16 + l16;
#pragma unroll
            for (int r = 0; r < 4; ++r)
                vbf[((size_t)b * NC + row0 + rt * 16 + g4 * 4 + r) * NHW + n] =
                    f2bf(acc[rt][ntl][r] + b4[r]);
        }
    }
}

// ---------------- attn: shared-KV flash attention (unchanged from r3) -------
__global__ __launch_bounds__(512, 2) void attn(
    const unsigned short* __restrict__ qt, const unsigned short* __restrict__ kt,
    const unsigned short* __restrict__ vbf, const float* __restrict__ x,
    const float* __restrict__ gamma, float* __restrict__ out)
{
    const int b    = blockIdx.x >> 6;
    const int nt64 = blockIdx.x & 63;
    const int tid  = threadIdx.x;
    const int wv   = tid >> 6;       // 0..7
    const int rg   = wv >> 1;        // q-row group (16 rows)
    const int cg   = wv & 1;         // c-half (128 channels)
    const int lane = tid & 63;
    const int l16  = lane & 15;
    const int g4   = lane >> 4;

    __shared__ alignas(16) unsigned short VsL[2][16384]; // V [c][64m], slot-swizzled
    __shared__ alignas(16) unsigned short KsL[2][2048];  // K [64m][32ch] linear

    const unsigned short* ktb = kt  + (size_t)b * NHW * NC8;
    const unsigned short* vbb = vbf + (size_t)b * NC  * NHW;

    const int nrow0 = nt64 * 64 + rg * 16;
    const bf16x8 qfrag = *(const bf16x8*)(qt + ((size_t)b * NHW + nrow0 + l16) * NC8 + g4 * 8);

    bf16x8 ones;
#pragma unroll
    for (int j = 0; j < 8; ++j) ones[j] = (short)0x3F80;

    f32x4 z = {0.f, 0.f, 0.f, 0.f};
    f32x4 acc[8];
#pragma unroll
    for (int ct = 0; ct < 8; ++ct) acc[ct] = z;
    f32x4 accl = z;            // row-sums L via ones-MFMA (rows = g4*4+r)
    float mrun = -1e30f;       // running max for row n = l16

    auto stage = [&](int buf, int m0) {
#pragma unroll
        for (int i = 0; i < 4; ++i) {
            const int ob = i * 8192 + tid * 16;   // byte offset in V buf
            const int c  = ob >> 7;
            const int s  = (ob >> 4) & 7;
            const int mg = s ^ (c & 7);
            glds16((char*)&VsL[buf][0] + ob, vbb + (size_t)c * NHW + m0 + mg * 8);
        }
#pragma unroll
        for (int i = 0; i < 2; ++i) {
            const int ob = i * 2048 + tid * 4;    // byte offset in K buf
            glds4((char*)&KsL[buf][0] + ob, ktb + (size_t)m0 * NC8 + ob / 2);
        }
    };

    stage(0, 0);

    for (int t = 0; t < 64; ++t) {
        const int cur = t & 1;
        if (t < 63) {
            stage(cur ^ 1, (t + 1) * MSTEP);
            asm volatile("s_waitcnt vmcnt(6)" ::: "memory");  // current tile landed
        } else {
            asm volatile("s_waitcnt vmcnt(0)" ::: "memory");
        }
        __builtin_amdgcn_s_barrier();
        asm volatile("" ::: "memory");

        const unsigned short* KsC = &KsL[cur][0];
        const unsigned short* VsC = &VsL[cur][0];

        // swapped QK^T: e[mt] rows = m (g4*4+r), cols = n (l16)
        f32x4 e[4];
#pragma unroll
        for (int mt = 0; mt < 4; ++mt) {
            bf16x8 kf = *(const bf16x8*)&KsC[(mt * 16 + l16) * NC8 + g4 * 8];
            e[mt] = __builtin_amdgcn_mfma_f32_16x16x32_bf16(kf, qfrag, z, 0, 0, 0);
        }

        float pmax = e[0][0];
#pragma unroll
        for (int mt = 0; mt < 4; ++mt)
#pragma unroll
            for (int r = 0; r < 4; ++r) pmax = fmaxf(pmax, e[mt][r]);
        pmax = fmaxf(pmax, __shfl_xor(pmax, 16));
        pmax = fmaxf(pmax, __shfl_xor(pmax, 32));

        if (__any(pmax - mrun > 8.0f)) {          // defer-max (T13)
            const float mnew = fmaxf(mrun, pmax);
            const float scl  = __expf(mrun - mnew);
            f32x4 sv;
#pragma unroll
            for (int r = 0; r < 4; ++r) sv[r] = __shfl(scl, g4 * 4 + r);
#pragma unroll
            for (int ct = 0; ct < 8; ++ct) acc[ct] *= sv;
            accl *= sv;
            mrun = mnew;
        }

        unsigned pkw[4][2];
#pragma unroll
        for (int mt = 0; mt < 4; ++mt) {
            const float p0 = __expf(e[mt][0] - mrun);
            const float p1 = __expf(e[mt][1] - mrun);
            const float p2 = __expf(e[mt][2] - mrun);
            const float p3 = __expf(e[mt][3] - mrun);
            pkw[mt][0] = packbf2(p0, p1);
            pkw[mt][1] = packbf2(p2, p3);
        }

        // PV per k-half h: A-frag word w <- m = h*32 + g4*8 + 2w
#pragma unroll
        for (int h = 0; h < 2; ++h) {
            union { unsigned u[4]; bf16x8 v; } pa;
#pragma unroll
            for (int w = 0; w < 4; ++w) {
                const int src = l16 + (((g4 & 1) * 2 + (w >> 1)) << 4);
                const unsigned vA = (unsigned)__shfl((int)pkw[2 * h + 0][w & 1], src);
                const unsigned vB = (unsigned)__shfl((int)pkw[2 * h + 1][w & 1], src);
                pa.u[w] = (g4 < 2) ? vA : vB;
            }
            accl = __builtin_amdgcn_mfma_f32_16x16x32_bf16(pa.v, ones, accl, 0, 0, 0);
#pragma unroll
            for (int ct = 0; ct < 8; ++ct) {
                const int c_loc = cg * 128 + ct * 16 + l16;
                const int sp = (h * 4 + g4) ^ (l16 & 7);   // unswizzle slot
                bf16x8 vf = *(const bf16x8*)&VsC[c_loc * 64 + sp * 8];
                acc[ct] = __builtin_amdgcn_mfma_f32_16x16x32_bf16(pa.v, vf, acc[ct], 0, 0, 0);
            }
        }

        asm volatile("" ::: "memory");
        __builtin_amdgcn_s_barrier();
    }

    const float ga = gamma[0];
    f32x4 il;
#pragma unroll
    for (int r = 0; r < 4; ++r) il[r] = ga / accl[r];
#pragma unroll
    for (int ct = 0; ct < 8; ++ct) {
        const int c = cg * 128 + ct * 16 + l16;
        const size_t o = ((size_t)b * NC + c) * NHW + nrow0 + g4 * 4;
        f32x4 xv = *(const f32x4*)(x + o);
        f32x4 res;
#pragma unroll
        for (int r = 0; r < 4; ++r) res[r] = fmaf(acc[ct][r], il[r], xv[r]);
        *(f32x4*)(out + o) = res;
    }
}

extern "C" void kernel_launch(void* const* d_in, const int* in_sizes, int n_in,
                              void* d_out, int out_size, void* d_ws, size_t ws_size,
                              hipStream_t stream) {
    const float* x     = (const float*)d_in[0];
    const float* g     = (const float*)d_in[1];
    const float* qw    = (const float*)d_in[2];
    const float* qb    = (const float*)d_in[3];
    const float* kw    = (const float*)d_in[4];
    const float* kb    = (const float*)d_in[5];
    const float* vw    = (const float*)d_in[6];
    const float* vb    = (const float*)d_in[7];
    const float* gamma = (const float*)d_in[8];
    float* out = (float*)d_out;

    unsigned short* qt  = (unsigned short*)d_ws;
    unsigned short* kt  = qt + (size_t)NB * NHW * NC8;
    unsigned short* vbf = kt + (size_t)NB * NHW * NC8;

    qk_proj<<<dim3(NB * (NHW / 64), 2), 512, 0, stream>>>(x, g, qw, qb, kw, kb, qt, kt);
    v_proj <<<dim3(NB * (NHW / 128), 8), 256, 0, stream>>>(g, vw, vb, vbf);
    attn   <<<NB * (NHW / 64), 512, 0, stream>>>(qt, kt, vbf, x, gamma, out);
}